// Round 8
// baseline (1047.680 us; speedup 1.0000x reference)
//
#include <hip/hip_runtime.h>
#include <hip/hip_bf16.h>

#define HD 128
#define LN_EPS 1e-5f

typedef __attribute__((ext_vector_type(8))) short short8;
typedef __attribute__((ext_vector_type(4))) float f32x4;

__device__ __forceinline__ unsigned short f2bf(float f) {
    union { float f; unsigned u; } v; v.f = f;
    unsigned r = (v.u + 0x7fffu + ((v.u >> 16) & 1u)) >> 16;
    return (unsigned short)r;
}

// hardware packed fp32->bf16 (RNE), 1 instr for 2 values
__device__ __forceinline__ unsigned cvtpk(float lo, float hi) {
    unsigned r;
    asm("v_cvt_pk_bf16_f32 %0, %1, %2" : "=v"(r) : "v"(lo), "v"(hi));
    return r;
}
// packed bf16(|lo|, |hi|) via VOP3 abs input modifiers
__device__ __forceinline__ unsigned cvtpk_abs(float lo, float hi) {
    unsigned r;
    asm("v_cvt_pk_bf16_f32 %0, abs(%1), abs(%2)" : "=v"(r) : "v"(lo), "v"(hi));
    return r;
}

__device__ __forceinline__ float wave_sum_all(float v) {
    #pragma unroll
    for (int o = 32; o > 0; o >>= 1) v += __shfl_xor(v, o);
    return v;
}

// ---------------- W1 (L x 384x128 f32, row-major) -> bf16 fragment-major, all layers
__global__ __launch_bounds__(256) void w1bf_kernel(
    const float* __restrict__ W1, unsigned short* __restrict__ out, int total)
{
    int idx = blockIdx.x * 256 + threadIdx.x;
    if (idx >= total) return;
    int lw  = idx / 49152;
    int rem = idx - lw * 49152;
    int j  = rem & 7;
    int c  = (rem >> 3) & 15;
    int ks = (rem >> 7) & 3;
    int ct = (rem >> 9) & 7;
    int q  = rem >> 12;
    out[idx] = f2bf(W1[(size_t)lw * 49152 + (size_t)(q * 32 + ks * 8 + j) * 128 + ct * 16 + c]);
}

// ---------------- fp32 GEMM: out[N][128] = cat(in0,in1)[N][K] @ W[K][128] (+bias)(+res)
// optional fused LN+relu epilogue (g != nullptr). Wave owns 8 rows.
__global__ __launch_bounds__(256) void gemm_rows_kernel(
    const float* __restrict__ in0, int s0, const float* __restrict__ in1, int s1,
    const float* __restrict__ W, const float* __restrict__ bias,
    const float* __restrict__ res, const float* __restrict__ g,
    const float* __restrict__ bln, float* __restrict__ out, int N)
{
    __shared__ __align__(16) float rows[4][8][256];
    int tid = threadIdx.x, wv = tid >> 6, lane = tid & 63;
    int rbase = (blockIdx.x * 4 + wv) * 8;
    if (rbase >= N) return;
    int K = in1 ? 256 : 128;
    int r = lane >> 3, seg = lane & 7;
    int row = min(rbase + r, N - 1);
    {
        const float4* p = (const float4*)(in0 + (size_t)row * s0 + seg * 16);
        float4* q = (float4*)&rows[wv][r][seg * 16];
        #pragma unroll
        for (int i = 0; i < 4; i++) q[i] = p[i];
        if (in1) {
            const float4* p1 = (const float4*)(in1 + (size_t)row * s1 + seg * 16);
            float4* q1 = (float4*)&rows[wv][r][128 + seg * 16];
            #pragma unroll
            for (int i = 0; i < 4; i++) q1[i] = p1[i];
        }
    }
    asm volatile("s_waitcnt lgkmcnt(0)" ::: "memory");
    float2 acc[8];
    float2 bv = make_float2(0.f, 0.f);
    if (bias) bv = *(const float2*)(bias + 2 * lane);
    #pragma unroll
    for (int t = 0; t < 8; t++) acc[t] = bv;
    for (int k = 0; k < K; k += 4) {
        float2 w0 = *(const float2*)(W + (size_t)(k + 0) * 128 + 2 * lane);
        float2 w1 = *(const float2*)(W + (size_t)(k + 1) * 128 + 2 * lane);
        float2 w2 = *(const float2*)(W + (size_t)(k + 2) * 128 + 2 * lane);
        float2 w3 = *(const float2*)(W + (size_t)(k + 3) * 128 + 2 * lane);
        #pragma unroll
        for (int t = 0; t < 8; t++) {
            float4 a = *(const float4*)&rows[wv][t][k];
            acc[t].x = fmaf(a.x, w0.x, acc[t].x); acc[t].y = fmaf(a.x, w0.y, acc[t].y);
            acc[t].x = fmaf(a.y, w1.x, acc[t].x); acc[t].y = fmaf(a.y, w1.y, acc[t].y);
            acc[t].x = fmaf(a.z, w2.x, acc[t].x); acc[t].y = fmaf(a.z, w2.y, acc[t].y);
            acc[t].x = fmaf(a.w, w3.x, acc[t].x); acc[t].y = fmaf(a.w, w3.y, acc[t].y);
        }
    }
    if (res) {
        #pragma unroll
        for (int t = 0; t < 8; t++) {
            int rw = rbase + t;
            if (rw < N) {
                float2 rv = *(const float2*)(res + (size_t)rw * 128 + 2 * lane);
                acc[t].x += rv.x; acc[t].y += rv.y;
            }
        }
    }
    if (g) {   // fused LN + relu
        float2 gv = *(const float2*)(g + 2 * lane);
        float2 lv = *(const float2*)(bln + 2 * lane);
        #pragma unroll
        for (int t = 0; t < 8; t++) {
            int rw = rbase + t;
            if (rw >= N) break;
            float s  = wave_sum_all(acc[t].x + acc[t].y);
            float s2 = wave_sum_all(acc[t].x * acc[t].x + acc[t].y * acc[t].y);
            float mu = s * (1.f / 128.f);
            float var = s2 * (1.f / 128.f) - mu * mu;
            float rs = rsqrtf(var + LN_EPS);
            float2 y;
            y.x = fmaxf((acc[t].x - mu) * rs * gv.x + lv.x, 0.f);
            y.y = fmaxf((acc[t].y - mu) * rs * gv.y + lv.y, 0.f);
            *(float2*)(out + (size_t)rw * 128 + 2 * lane) = y;
        }
    } else {
        #pragma unroll
        for (int t = 0; t < 8; t++) {
            int rw = rbase + t;
            if (rw < N) *(float2*)(out + (size_t)rw * 128 + 2 * lane) = acc[t];
        }
    }
}

// ---------------- CSR build ----------------
__global__ __launch_bounds__(256) void hist_kernel(
    const int* __restrict__ dstA, int* __restrict__ cnt, int E, int Etot)
{
    for (int e = blockIdx.x * 256 + threadIdx.x; e < Etot; e += gridDim.x * 256) {
        int di = (e < E) ? dstA[e] : (e - E);
        atomicAdd(&cnt[di], 1);
    }
}

__global__ __launch_bounds__(256) void scan_kernel(
    const int* __restrict__ cnt, int* __restrict__ rowptr, int* __restrict__ cursor,
    int N, int Etot)
{
    __shared__ int ls[256];
    int t = threadIdx.x;
    int chunk = (N + 255) / 256;
    int lo = t * chunk, hi = min(lo + chunk, N);
    int s = 0;
    for (int i = lo; i < hi; i++) s += cnt[i];
    ls[t] = s;
    __syncthreads();
    for (int off = 1; off < 256; off <<= 1) {
        int v = (t >= off) ? ls[t - off] : 0;
        __syncthreads();
        ls[t] += v;
        __syncthreads();
    }
    int run = ls[t] - s;
    for (int i = lo; i < hi; i++) {
        rowptr[i] = run; cursor[i] = run;
        run += cnt[i];
    }
    if (t == 0) rowptr[N] = Etot;
}

// emits CSR-ordered src/dst arrays (sorted by dst)
__global__ __launch_bounds__(256) void scatter_kernel(
    const int* __restrict__ srcA, const int* __restrict__ dstA,
    int* __restrict__ cursor, int* __restrict__ esrc, int* __restrict__ edst,
    int E, int Etot)
{
    for (int e = blockIdx.x * 256 + threadIdx.x; e < Etot; e += gridDim.x * 256) {
        int si = (e < E) ? srcA[e] : (e - E);
        int di = (e < E) ? dstA[e] : (e - E);
        int pos = atomicAdd(&cursor[di], 1);
        esrc[pos] = si;
        edst[pos] = di;
    }
}

// ---------------- fused edge kernel (CSR order):
// scores via MFMA (sim=[x_i|x_j|d], K=384), then agg[dst] += score*M[src]
// with run-length register accumulation + atomic flush per dst-run.
// LDS planes: xi +0, xj +16384, d +32768 (plane = 64 rows x 256 B, XOR swizzle).
__global__ __launch_bounds__(256) void edge_fused_kernel(
    const float* __restrict__ h,
    const int* __restrict__ esrc, const int* __restrict__ edst,
    const float* __restrict__ M,
    const unsigned short* __restrict__ w1bf, const float* __restrict__ b1,
    const float* __restrict__ W2, const float* __restrict__ b2p,
    float* __restrict__ agg, int Etot)
{
    __shared__ __align__(16) short sim[3][64][128];   // 48 KB
    __shared__ float pl[4][64];
    int tid = threadIdx.x, wv = tid >> 6, lane = tid & 63;
    char* simb = (char*)sim;

    // W1 fragments: 12 K-tiles x 2 col-tiles
    short8 wf[12][2];
    {
        int ks = lane >> 4, c = lane & 15;
        #pragma unroll
        for (int q = 0; q < 12; q++)
            #pragma unroll
            for (int n = 0; n < 2; n++) {
                int ct = wv * 2 + n;
                wf[q][n] = *(const short8*)(w1bf + (size_t)(((q * 8 + ct) * 4 + ks) * 128 + c * 8));
            }
    }
    float b1x = b1[wv * 32 + (lane & 15)],  b1y = b1[wv * 32 + 16 + (lane & 15)];
    float w2x = W2[wv * 32 + (lane & 15)],  w2y = W2[wv * 32 + 16 + (lane & 15)];
    float b2 = b2p[0];

    int ntiles = (Etot + 63) >> 6;
    int t0 = (int)(((long long)ntiles * blockIdx.x) / gridDim.x);
    int t1 = (int)(((long long)ntiles * (blockIdx.x + 1)) / gridDim.x);

    for (int tile = t0; tile < t1; tile++) {
        int ebase = tile << 6;
        // ---- stage 64 edges x (xi|xj|d) bf16; thread: 1 edge, 32 cols (fp32 source)
        {
            int el = tid >> 2, seg = tid & 3;
            int e = ebase + el; if (e >= Etot) e = Etot - 1;
            int si = esrc[e];
            int di = edst[e];
            const float4* xi = (const float4*)(h + (size_t)di * 128 + seg * 32);
            const float4* xj = (const float4*)(h + (size_t)si * 128 + seg * 32);
            int rowoff = el * 256, sw = (el & 7) << 4;
            #pragma unroll
            for (int gseg = 0; gseg < 4; gseg++) {
                float4 a0 = xi[2 * gseg], a1 = xi[2 * gseg + 1];
                float4 b0 = xj[2 * gseg], b1v = xj[2 * gseg + 1];
                uint4 pa, pb, pd;
                pa.x = cvtpk(a0.x, a0.y);  pa.y = cvtpk(a0.z, a0.w);
                pa.z = cvtpk(a1.x, a1.y);  pa.w = cvtpk(a1.z, a1.w);
                pb.x = cvtpk(b0.x, b0.y);  pb.y = cvtpk(b0.z, b0.w);
                pb.z = cvtpk(b1v.x, b1v.y); pb.w = cvtpk(b1v.z, b1v.w);
                pd.x = cvtpk_abs(a0.x - b0.x, a0.y - b0.y);
                pd.y = cvtpk_abs(a0.z - b0.z, a0.w - b0.w);
                pd.z = cvtpk_abs(a1.x - b1v.x, a1.y - b1v.y);
                pd.w = cvtpk_abs(a1.z - b1v.z, a1.w - b1v.w);
                int off = rowoff + ((seg * 64 + gseg * 16) ^ sw);
                *(uint4*)(simb + off)         = pa;
                *(uint4*)(simb + 16384 + off) = pb;
                *(uint4*)(simb + 32768 + off) = pd;
            }
        }
        __syncthreads();
        // ---- MFMA: C[64 edges][32 cols] per wave
        f32x4 acc[4][2];
        #pragma unroll
        for (int m = 0; m < 4; m++)
            #pragma unroll
            for (int n = 0; n < 2; n++)
                #pragma unroll
                for (int r = 0; r < 4; r++) acc[m][n][r] = 0.f;
        #pragma unroll
        for (int q = 0; q < 12; q++) {
            int third = q >> 2;
            int kin = ((q & 3) * 64 + (lane >> 4) * 16);
            short8 af[4];
            #pragma unroll
            for (int m = 0; m < 4; m++) {
                int el = m * 16 + (lane & 15);
                int addr = third * 16384 + el * 256 + (kin ^ ((el & 7) << 4));
                af[m] = *(const short8*)(simb + addr);
            }
            #pragma unroll
            for (int m = 0; m < 4; m++)
                #pragma unroll
                for (int n = 0; n < 2; n++)
                    acc[m][n] = __builtin_amdgcn_mfma_f32_16x16x32_bf16(af[m], wf[q][n], acc[m][n], 0, 0, 0);
        }
        // ---- relu + W2 dot + 16-lane reduce -> pl[wv][edge-in-tile]
        #pragma unroll
        for (int m = 0; m < 4; m++) {
            #pragma unroll
            for (int r = 0; r < 4; r++) {
                float v = fmaxf(acc[m][0][r] + b1x, 0.f) * w2x
                        + fmaxf(acc[m][1][r] + b1y, 0.f) * w2y;
                v += __shfl_xor(v, 1); v += __shfl_xor(v, 2);
                v += __shfl_xor(v, 4); v += __shfl_xor(v, 8);
                if ((lane & 15) == 0) pl[wv][m * 16 + (lane >> 4) * 4 + r] = v;
            }
        }
        __syncthreads();
        // ---- fused aggregation: wave wv owns edges [wv*16, wv*16+16) of this tile.
        // CSR order => dst monotone; run-length accumulate, atomic flush per run.
        {
            int e0 = ebase + wv * 16;
            int scnt = min(16, Etot - e0);
            if (scnt > 0) {
                int li = lane & 15;
                int ce = min(e0 + li, Etot - 1);
                int sv = esrc[ce];
                int dv = edst[ce];
                int idx = wv * 16 + li;
                float z = pl[0][idx] + pl[1][idx] + pl[2][idx] + pl[3][idx] + b2;
                float sci = 1.f / (1.f + __expf(-z));
                float2 racc = make_float2(0.f, 0.f);
                int cur = __shfl(dv, 0);
                for (int i = 0; i < scnt; i++) {
                    int di = __shfl(dv, i);
                    float s = __shfl(sci, i);
                    int si = __shfl(sv, i);
                    if (di != cur) {
                        atomicAdd(&agg[(size_t)cur * 128 + 2 * lane],     racc.x);
                        atomicAdd(&agg[(size_t)cur * 128 + 2 * lane + 1], racc.y);
                        racc = make_float2(0.f, 0.f);
                        cur = di;
                    }
                    float2 mv = *(const float2*)(M + (size_t)si * 128 + 2 * lane);
                    racc.x = fmaf(s, mv.x, racc.x);
                    racc.y = fmaf(s, mv.y, racc.y);
                }
                atomicAdd(&agg[(size_t)cur * 128 + 2 * lane],     racc.x);
                atomicAdd(&agg[(size_t)cur * 128 + 2 * lane + 1], racc.y);
            }
        }
        // no barrier needed here: next tile's pl write is after its own __syncthreads
    }
}

// ---------------- classifier
__global__ __launch_bounds__(256) void cls_kernel(
    const float* __restrict__ hin, const float* __restrict__ W1,
    const float* __restrict__ b1, const float* __restrict__ W2,
    const float* __restrict__ b2, float* __restrict__ out, int N)
{
    __shared__ __align__(16) float w1[HD * 64];
    __shared__ __align__(16) float w2[64 * 40];
    __shared__ __align__(16) float hs[4][HD];
    __shared__ float ts[4][64];
    for (int i = threadIdx.x; i < HD * 64; i += 256) w1[i] = W1[i];
    for (int i = threadIdx.x; i < 64 * 40; i += 256) w2[i] = W2[i];
    int sub = threadIdx.x >> 6, t = threadIdx.x & 63;
    float b1j = b1[t];
    float b2j = (t < 40) ? b2[t] : 0.f;
    __syncthreads();
    for (int base = blockIdx.x * 4; base < N; base += gridDim.x * 4) {
        int i = base + sub; bool val = i < N;
        if (val) { hs[sub][t] = hin[(size_t)i * HD + t]; hs[sub][64 + t] = hin[(size_t)i * HD + 64 + t]; }
        __syncthreads();
        float acc = b1j;
        const float* hr = hs[sub];
        #pragma unroll 8
        for (int k = 0; k < HD; k += 4) {
            float4 hv = *(const float4*)(hr + k);
            acc = fmaf(hv.x, w1[(k + 0) * 64 + t], acc);
            acc = fmaf(hv.y, w1[(k + 1) * 64 + t], acc);
            acc = fmaf(hv.z, w1[(k + 2) * 64 + t], acc);
            acc = fmaf(hv.w, w1[(k + 3) * 64 + t], acc);
        }
        ts[sub][t] = fmaxf(acc, 0.f);
        __syncthreads();
        if (val && t < 40) {
            float o = b2j;
            const float* tr = ts[sub];
            #pragma unroll 8
            for (int k = 0; k < 64; k++) o = fmaf(tr[k], w2[k * 40 + t], o);
            out[(size_t)i * 40 + t] = o;
        }
        __syncthreads();
    }
}

extern "C" void kernel_launch(void* const* d_in, const int* in_sizes, int n_in,
                              void* d_out, int out_size, void* d_ws, size_t ws_size,
                              hipStream_t stream)
{
    const float* x      = (const float*)d_in[0];
    const int*   ei     = (const int*)d_in[1];
    const float* proj_W = (const float*)d_in[2];
    const float* proj_b = (const float*)d_in[3];
    const float* ln0_g  = (const float*)d_in[4];
    const float* ln0_b  = (const float*)d_in[5];
    const float* sim_W1 = (const float*)d_in[6];
    const float* sim_b1 = (const float*)d_in[7];
    const float* sim_W2 = (const float*)d_in[8];
    const float* sim_b2 = (const float*)d_in[9];
    const float* W_msg  = (const float*)d_in[10];
    const float* W_upd  = (const float*)d_in[11];
    const float* b_upd  = (const float*)d_in[12];
    const float* ln_g   = (const float*)d_in[13];
    const float* ln_b   = (const float*)d_in[14];
    const float* cls_W1 = (const float*)d_in[15];
    const float* cls_b1 = (const float*)d_in[16];
    const float* cls_W2 = (const float*)d_in[17];
    const float* cls_b2 = (const float*)d_in[18];

    int N = in_sizes[0] / 256;
    int E = in_sizes[1] / 2;
    int L = in_sizes[6] / (3 * HD * HD);
    int Etot = E + N;
    const int* srcA = ei;
    const int* dstA = ei + E;

    float* ws = (float*)d_ws;
    size_t nh = (size_t)N * HD;
    float* h     = ws;
    float* Mt    = h + nh;
    float* agg   = Mt + nh;
    unsigned short* w1bf = (unsigned short*)(agg + nh);   // L*49152 shorts
    int*   cnt    = (int*)(w1bf + (size_t)L * 49152);
    int*   rowptr = cnt + N;
    int*   cursor = rowptr + N + 1;
    int*   esrc   = cursor + N;
    int*   edst   = esrc + Etot;

    int gemm_blocks = (N + 31) / 32;

    // CSR build (edge_index constant across layers)
    hipMemsetAsync(cnt, 0, (size_t)N * sizeof(int), stream);
    hist_kernel<<<512, 256, 0, stream>>>(dstA, cnt, E, Etot);
    scan_kernel<<<1, 256, 0, stream>>>(cnt, rowptr, cursor, N, Etot);
    scatter_kernel<<<512, 256, 0, stream>>>(srcA, dstA, cursor, esrc, edst, E, Etot);

    // all layers' W1 -> bf16 fragment-major, once
    int w1_total = L * 49152;
    w1bf_kernel<<<(w1_total + 255) / 256, 256, 0, stream>>>(sim_W1, w1bf, w1_total);

    // h = relu(LN(x @ proj_W + b))   (LN fused)
    gemm_rows_kernel<<<gemm_blocks, 256, 0, stream>>>(x, 256, x + 128, 256, proj_W, proj_b,
                                                      nullptr, ln0_g, ln0_b, h, N);

    for (int l = 0; l < L; l++) {
        // M = h @ W_msg
        gemm_rows_kernel<<<gemm_blocks, 256, 0, stream>>>(h, 128, nullptr, 0,
                                                          W_msg + (size_t)l * HD * HD,
                                                          nullptr, nullptr, nullptr, nullptr, Mt, N);
        hipMemsetAsync(agg, 0, nh * sizeof(float), stream);
        // fused: edge scores (bf16 MFMA) + agg accumulation
        edge_fused_kernel<<<768, 256, 0, stream>>>(h, esrc, edst, Mt,
                                                   w1bf + (size_t)l * 49152, sim_b1 + l * HD,
                                                   sim_W2 + l * HD, sim_b2 + l, agg, Etot);
        // h = relu(LN(cat(h,agg)@W_upd + b + h))  (LN fused, in-place per-row)
        gemm_rows_kernel<<<gemm_blocks, 256, 0, stream>>>(h, 128, agg, 128,
                                                          W_upd + (size_t)l * 2 * HD * HD,
                                                          b_upd + l * HD, h,
                                                          ln_g + l * HD, ln_b + l * HD, h, N);
    }
    cls_kernel<<<768, 256, 0, stream>>>(h, cls_W1, cls_b1, cls_W2, cls_b2, (float*)d_out, N);
}

// Round 9
// 618.052 us; speedup vs baseline: 1.6951x; 1.6951x over previous
//
#include <hip/hip_runtime.h>
#include <hip/hip_bf16.h>

#define HD 128
#define LN_EPS 1e-5f

typedef __attribute__((ext_vector_type(8))) short short8;
typedef __attribute__((ext_vector_type(4))) float f32x4;

__device__ __forceinline__ unsigned short f2bf(float f) {
    union { float f; unsigned u; } v; v.f = f;
    unsigned r = (v.u + 0x7fffu + ((v.u >> 16) & 1u)) >> 16;
    return (unsigned short)r;
}

__device__ __forceinline__ unsigned cvtpk(float lo, float hi) {
    unsigned r;
    asm("v_cvt_pk_bf16_f32 %0, %1, %2" : "=v"(r) : "v"(lo), "v"(hi));
    return r;
}
__device__ __forceinline__ unsigned cvtpk_abs(float lo, float hi) {
    unsigned r;
    asm("v_cvt_pk_bf16_f32 %0, abs(%1), abs(%2)" : "=v"(r) : "v"(lo), "v"(hi));
    return r;
}

__device__ __forceinline__ float wave_sum_all(float v) {
    #pragma unroll
    for (int o = 32; o > 0; o >>= 1) v += __shfl_xor(v, o);
    return v;
}

// ---------------- W1 (L x 384x128 f32) -> bf16 fragment-major, all layers
__global__ __launch_bounds__(256) void w1bf_kernel(
    const float* __restrict__ W1, unsigned short* __restrict__ out, int total)
{
    int idx = blockIdx.x * 256 + threadIdx.x;
    if (idx >= total) return;
    int lw  = idx / 49152;
    int rem = idx - lw * 49152;
    int j  = rem & 7;
    int c  = (rem >> 3) & 15;
    int ks = (rem >> 7) & 3;
    int ct = (rem >> 9) & 7;
    int q  = rem >> 12;
    out[idx] = f2bf(W1[(size_t)lw * 49152 + (size_t)(q * 32 + ks * 8 + j) * 128 + ct * 16 + c]);
}

// ---------------- copy W_upd[l][0:128] into wcomb[l][0:128]
__global__ __launch_bounds__(256) void copy_upd_kernel(
    const float* __restrict__ W_upd, float* __restrict__ wcomb, int total)
{
    int idx = blockIdx.x * 256 + threadIdx.x;
    if (idx >= total) return;
    int l = idx / 16384, r = idx - l * 16384;
    wcomb[(size_t)l * 32768 + r] = W_upd[(size_t)l * 32768 + r];
}

// ---------------- fp32 GEMM: out[N][128] = cat(in0,in1)[N][K] @ W[K][128] (+bias)(+res)
// optional fused LN+relu epilogue (g != nullptr). Wave owns 8 rows.
__global__ __launch_bounds__(256) void gemm_rows_kernel(
    const float* __restrict__ in0, int s0, const float* __restrict__ in1, int s1,
    const float* __restrict__ W, const float* __restrict__ bias,
    const float* __restrict__ res, const float* __restrict__ g,
    const float* __restrict__ bln, float* __restrict__ out, int N)
{
    __shared__ __align__(16) float rows[4][8][256];
    int tid = threadIdx.x, wv = tid >> 6, lane = tid & 63;
    int rbase = (blockIdx.x * 4 + wv) * 8;
    if (rbase >= N) return;
    int K = in1 ? 256 : 128;
    int r = lane >> 3, seg = lane & 7;
    int row = min(rbase + r, N - 1);
    {
        const float4* p = (const float4*)(in0 + (size_t)row * s0 + seg * 16);
        float4* q = (float4*)&rows[wv][r][seg * 16];
        #pragma unroll
        for (int i = 0; i < 4; i++) q[i] = p[i];
        if (in1) {
            const float4* p1 = (const float4*)(in1 + (size_t)row * s1 + seg * 16);
            float4* q1 = (float4*)&rows[wv][r][128 + seg * 16];
            #pragma unroll
            for (int i = 0; i < 4; i++) q1[i] = p1[i];
        }
    }
    asm volatile("s_waitcnt lgkmcnt(0)" ::: "memory");
    float2 acc[8];
    float2 bv = make_float2(0.f, 0.f);
    if (bias) bv = *(const float2*)(bias + 2 * lane);
    #pragma unroll
    for (int t = 0; t < 8; t++) acc[t] = bv;
    for (int k = 0; k < K; k += 4) {
        float2 w0 = *(const float2*)(W + (size_t)(k + 0) * 128 + 2 * lane);
        float2 w1 = *(const float2*)(W + (size_t)(k + 1) * 128 + 2 * lane);
        float2 w2 = *(const float2*)(W + (size_t)(k + 2) * 128 + 2 * lane);
        float2 w3 = *(const float2*)(W + (size_t)(k + 3) * 128 + 2 * lane);
        #pragma unroll
        for (int t = 0; t < 8; t++) {
            float4 a = *(const float4*)&rows[wv][t][k];
            acc[t].x = fmaf(a.x, w0.x, acc[t].x); acc[t].y = fmaf(a.x, w0.y, acc[t].y);
            acc[t].x = fmaf(a.y, w1.x, acc[t].x); acc[t].y = fmaf(a.y, w1.y, acc[t].y);
            acc[t].x = fmaf(a.z, w2.x, acc[t].x); acc[t].y = fmaf(a.z, w2.y, acc[t].y);
            acc[t].x = fmaf(a.w, w3.x, acc[t].x); acc[t].y = fmaf(a.w, w3.y, acc[t].y);
        }
    }
    if (res) {
        #pragma unroll
        for (int t = 0; t < 8; t++) {
            int rw = rbase + t;
            if (rw < N) {
                float2 rv = *(const float2*)(res + (size_t)rw * 128 + 2 * lane);
                acc[t].x += rv.x; acc[t].y += rv.y;
            }
        }
    }
    if (g) {
        float2 gv = *(const float2*)(g + 2 * lane);
        float2 lv = *(const float2*)(bln + 2 * lane);
        #pragma unroll
        for (int t = 0; t < 8; t++) {
            int rw = rbase + t;
            if (rw >= N) break;
            float s  = wave_sum_all(acc[t].x + acc[t].y);
            float s2 = wave_sum_all(acc[t].x * acc[t].x + acc[t].y * acc[t].y);
            float mu = s * (1.f / 128.f);
            float var = s2 * (1.f / 128.f) - mu * mu;
            float rs = rsqrtf(var + LN_EPS);
            float2 y;
            y.x = fmaxf((acc[t].x - mu) * rs * gv.x + lv.x, 0.f);
            y.y = fmaxf((acc[t].y - mu) * rs * gv.y + lv.y, 0.f);
            *(float2*)(out + (size_t)rw * 128 + 2 * lane) = y;
        }
    } else {
        #pragma unroll
        for (int t = 0; t < 8; t++) {
            int rw = rbase + t;
            if (rw < N) *(float2*)(out + (size_t)rw * 128 + 2 * lane) = acc[t];
        }
    }
}

// ---------------- CSR build ----------------
__global__ __launch_bounds__(256) void hist_kernel(
    const int* __restrict__ dstA, int* __restrict__ cnt, int E, int Etot)
{
    for (int e = blockIdx.x * 256 + threadIdx.x; e < Etot; e += gridDim.x * 256) {
        int di = (e < E) ? dstA[e] : (e - E);
        atomicAdd(&cnt[di], 1);
    }
}

__global__ __launch_bounds__(256) void scan_kernel(
    const int* __restrict__ cnt, int* __restrict__ rowptr, int* __restrict__ cursor,
    int N, int Etot)
{
    __shared__ int ls[256];
    int t = threadIdx.x;
    int chunk = (N + 255) / 256;
    int lo = t * chunk, hi = min(lo + chunk, N);
    int s = 0;
    for (int i = lo; i < hi; i++) s += cnt[i];
    ls[t] = s;
    __syncthreads();
    for (int off = 1; off < 256; off <<= 1) {
        int v = (t >= off) ? ls[t - off] : 0;
        __syncthreads();
        ls[t] += v;
        __syncthreads();
    }
    int run = ls[t] - s;
    for (int i = lo; i < hi; i++) {
        rowptr[i] = run; cursor[i] = run;
        run += cnt[i];
    }
    if (t == 0) rowptr[N] = Etot;
}

// emits CSR-ordered src/dst arrays (sorted by dst)
__global__ __launch_bounds__(256) void scatter_kernel(
    const int* __restrict__ srcA, const int* __restrict__ dstA,
    int* __restrict__ cursor, int* __restrict__ esrc, int* __restrict__ edst,
    int E, int Etot)
{
    for (int e = blockIdx.x * 256 + threadIdx.x; e < Etot; e += gridDim.x * 256) {
        int si = (e < E) ? srcA[e] : (e - E);
        int di = (e < E) ? dstA[e] : (e - E);
        int pos = atomicAdd(&cursor[di], 1);
        esrc[pos] = si;
        edst[pos] = di;
    }
}

// ---------------- edge scores via MFMA (CSR edge order)
// sim=[x_i|x_j|d] (K=384) from fp32 h, HW cvt_pk; hmid=relu(sim@W1+b1); score=sigmoid(hmid@W2+b2)
// LDS planes: xi +0, xj +16384, d +32768 (plane = 64 rows x 256 B, XOR swizzle).
__global__ __launch_bounds__(256) void edge_mfma_kernel(
    const float* __restrict__ h,
    const int* __restrict__ esrc, const int* __restrict__ edst,
    const unsigned short* __restrict__ w1bf, const float* __restrict__ b1,
    const float* __restrict__ W2, const float* __restrict__ b2p,
    float* __restrict__ score, int Etot)
{
    __shared__ __align__(16) short sim[3][64][128];   // 48 KB
    __shared__ float pl[4][64];
    int tid = threadIdx.x, wv = tid >> 6, lane = tid & 63;
    char* simb = (char*)sim;

    short8 wf[12][2];
    {
        int ks = lane >> 4, c = lane & 15;
        #pragma unroll
        for (int q = 0; q < 12; q++)
            #pragma unroll
            for (int n = 0; n < 2; n++) {
                int ct = wv * 2 + n;
                wf[q][n] = *(const short8*)(w1bf + (size_t)(((q * 8 + ct) * 4 + ks) * 128 + c * 8));
            }
    }
    float b1x = b1[wv * 32 + (lane & 15)],  b1y = b1[wv * 32 + 16 + (lane & 15)];
    float w2x = W2[wv * 32 + (lane & 15)],  w2y = W2[wv * 32 + 16 + (lane & 15)];
    float b2 = b2p[0];

    // XCD-aware bijective swizzle (gridDim.x % 8 == 0): contiguous tile chunk per block
    int nb = gridDim.x;
    int swz = (blockIdx.x & 7) * (nb >> 3) + (blockIdx.x >> 3);
    int ntiles = (Etot + 63) >> 6;
    int t0 = (int)(((long long)ntiles * swz) / nb);
    int t1 = (int)(((long long)ntiles * (swz + 1)) / nb);

    for (int tile = t0; tile < t1; tile++) {
        int ebase = tile << 6;
        {
            int el = tid >> 2, seg = tid & 3;
            int e = ebase + el; if (e >= Etot) e = Etot - 1;
            int si = esrc[e];
            int di = edst[e];
            const float4* xi = (const float4*)(h + (size_t)di * 128 + seg * 32);
            const float4* xj = (const float4*)(h + (size_t)si * 128 + seg * 32);
            int rowoff = el * 256, sw = (el & 7) << 4;
            #pragma unroll
            for (int gseg = 0; gseg < 4; gseg++) {
                float4 a0 = xi[2 * gseg], a1 = xi[2 * gseg + 1];
                float4 b0 = xj[2 * gseg], b1v = xj[2 * gseg + 1];
                uint4 pa, pb, pd;
                pa.x = cvtpk(a0.x, a0.y);  pa.y = cvtpk(a0.z, a0.w);
                pa.z = cvtpk(a1.x, a1.y);  pa.w = cvtpk(a1.z, a1.w);
                pb.x = cvtpk(b0.x, b0.y);  pb.y = cvtpk(b0.z, b0.w);
                pb.z = cvtpk(b1v.x, b1v.y); pb.w = cvtpk(b1v.z, b1v.w);
                pd.x = cvtpk_abs(a0.x - b0.x, a0.y - b0.y);
                pd.y = cvtpk_abs(a0.z - b0.z, a0.w - b0.w);
                pd.z = cvtpk_abs(a1.x - b1v.x, a1.y - b1v.y);
                pd.w = cvtpk_abs(a1.z - b1v.z, a1.w - b1v.w);
                int off = rowoff + ((seg * 64 + gseg * 16) ^ sw);
                *(uint4*)(simb + off)         = pa;
                *(uint4*)(simb + 16384 + off) = pb;
                *(uint4*)(simb + 32768 + off) = pd;
            }
        }
        __syncthreads();
        f32x4 acc[4][2];
        #pragma unroll
        for (int m = 0; m < 4; m++)
            #pragma unroll
            for (int n = 0; n < 2; n++)
                #pragma unroll
                for (int r = 0; r < 4; r++) acc[m][n][r] = 0.f;
        #pragma unroll
        for (int q = 0; q < 12; q++) {
            int third = q >> 2;
            int kin = ((q & 3) * 64 + (lane >> 4) * 16);
            short8 af[4];
            #pragma unroll
            for (int m = 0; m < 4; m++) {
                int el = m * 16 + (lane & 15);
                int addr = third * 16384 + el * 256 + (kin ^ ((el & 7) << 4));
                af[m] = *(const short8*)(simb + addr);
            }
            #pragma unroll
            for (int m = 0; m < 4; m++)
                #pragma unroll
                for (int n = 0; n < 2; n++)
                    acc[m][n] = __builtin_amdgcn_mfma_f32_16x16x32_bf16(af[m], wf[q][n], acc[m][n], 0, 0, 0);
        }
        #pragma unroll
        for (int m = 0; m < 4; m++) {
            #pragma unroll
            for (int r = 0; r < 4; r++) {
                float v = fmaxf(acc[m][0][r] + b1x, 0.f) * w2x
                        + fmaxf(acc[m][1][r] + b1y, 0.f) * w2y;
                v += __shfl_xor(v, 1); v += __shfl_xor(v, 2);
                v += __shfl_xor(v, 4); v += __shfl_xor(v, 8);
                if ((lane & 15) == 0) pl[wv][m * 16 + (lane >> 4) * 4 + r] = v;
            }
        }
        __syncthreads();
        if (tid < 64) {
            int e = ebase + tid;
            if (e < Etot) {
                float z = pl[0][tid] + pl[1][tid] + pl[2][tid] + pl[3][tid] + b2;
                score[e] = 1.f / (1.f + __expf(-z));
            }
        }
        __syncthreads();
    }
}

// ---------------- pre_agg[n] = sum over incoming CSR edges of score[pos]*h[esrc[pos]]
// (M-matmul folded into update GEMM via wcomb). 4-wide unroll for load ILP.
__global__ __launch_bounds__(256) void gather_kernel(
    const int* __restrict__ rowptr, const int* __restrict__ esrc,
    const float* __restrict__ score, const float* __restrict__ h,
    float* __restrict__ pre_agg, int N)
{
    int nb = gridDim.x;
    int bid = blockIdx.x;
    int swz = (bid & 7) * (nb >> 3) + (bid >> 3);
    int wvi = threadIdx.x >> 6, lane = threadIdx.x & 63;
    int node = swz * 4 + wvi;
    if (node >= N) return;
    int p0 = rowptr[node], p1 = rowptr[node + 1];
    float2 a0 = make_float2(0.f, 0.f), a1 = a0, a2 = a0, a3 = a0;
    for (int base = p0; base < p1; base += 64) {
        int cnt = min(64, p1 - base);
        int sidx = 0; float sc = 0.f;
        if (lane < cnt) {
            sidx = esrc[base + lane];
            sc = score[base + lane];
        }
        int i = 0;
        for (; i + 4 <= cnt; i += 4) {
            float s0 = __shfl(sc, i),     s1 = __shfl(sc, i + 1);
            float s2 = __shfl(sc, i + 2), s3 = __shfl(sc, i + 3);
            int r0 = __shfl(sidx, i),     r1 = __shfl(sidx, i + 1);
            int r2 = __shfl(sidx, i + 2), r3 = __shfl(sidx, i + 3);
            float2 v0 = *(const float2*)(h + (size_t)r0 * 128 + 2 * lane);
            float2 v1 = *(const float2*)(h + (size_t)r1 * 128 + 2 * lane);
            float2 v2 = *(const float2*)(h + (size_t)r2 * 128 + 2 * lane);
            float2 v3 = *(const float2*)(h + (size_t)r3 * 128 + 2 * lane);
            a0.x = fmaf(s0, v0.x, a0.x); a0.y = fmaf(s0, v0.y, a0.y);
            a1.x = fmaf(s1, v1.x, a1.x); a1.y = fmaf(s1, v1.y, a1.y);
            a2.x = fmaf(s2, v2.x, a2.x); a2.y = fmaf(s2, v2.y, a2.y);
            a3.x = fmaf(s3, v3.x, a3.x); a3.y = fmaf(s3, v3.y, a3.y);
        }
        for (; i < cnt; i++) {
            float s = __shfl(sc, i);
            int rr = __shfl(sidx, i);
            float2 v = *(const float2*)(h + (size_t)rr * 128 + 2 * lane);
            a0.x = fmaf(s, v.x, a0.x); a0.y = fmaf(s, v.y, a0.y);
        }
    }
    float2 o;
    o.x = (a0.x + a1.x) + (a2.x + a3.x);
    o.y = (a0.y + a1.y) + (a2.y + a3.y);
    *(float2*)(pre_agg + (size_t)node * 128 + 2 * lane) = o;
}

// ---------------- classifier
__global__ __launch_bounds__(256) void cls_kernel(
    const float* __restrict__ hin, const float* __restrict__ W1,
    const float* __restrict__ b1, const float* __restrict__ W2,
    const float* __restrict__ b2, float* __restrict__ out, int N)
{
    __shared__ __align__(16) float w1[HD * 64];
    __shared__ __align__(16) float w2[64 * 40];
    __shared__ __align__(16) float hs[4][HD];
    __shared__ float ts[4][64];
    for (int i = threadIdx.x; i < HD * 64; i += 256) w1[i] = W1[i];
    for (int i = threadIdx.x; i < 64 * 40; i += 256) w2[i] = W2[i];
    int sub = threadIdx.x >> 6, t = threadIdx.x & 63;
    float b1j = b1[t];
    float b2j = (t < 40) ? b2[t] : 0.f;
    __syncthreads();
    for (int base = blockIdx.x * 4; base < N; base += gridDim.x * 4) {
        int i = base + sub; bool val = i < N;
        if (val) { hs[sub][t] = hin[(size_t)i * HD + t]; hs[sub][64 + t] = hin[(size_t)i * HD + 64 + t]; }
        __syncthreads();
        float acc = b1j;
        const float* hr = hs[sub];
        #pragma unroll 8
        for (int k = 0; k < HD; k += 4) {
            float4 hv = *(const float4*)(hr + k);
            acc = fmaf(hv.x, w1[(k + 0) * 64 + t], acc);
            acc = fmaf(hv.y, w1[(k + 1) * 64 + t], acc);
            acc = fmaf(hv.z, w1[(k + 2) * 64 + t], acc);
            acc = fmaf(hv.w, w1[(k + 3) * 64 + t], acc);
        }
        ts[sub][t] = fmaxf(acc, 0.f);
        __syncthreads();
        if (val && t < 40) {
            float o = b2j;
            const float* tr = ts[sub];
            #pragma unroll 8
            for (int k = 0; k < 64; k++) o = fmaf(tr[k], w2[k * 40 + t], o);
            out[(size_t)i * 40 + t] = o;
        }
        __syncthreads();
    }
}

extern "C" void kernel_launch(void* const* d_in, const int* in_sizes, int n_in,
                              void* d_out, int out_size, void* d_ws, size_t ws_size,
                              hipStream_t stream)
{
    const float* x      = (const float*)d_in[0];
    const int*   ei     = (const int*)d_in[1];
    const float* proj_W = (const float*)d_in[2];
    const float* proj_b = (const float*)d_in[3];
    const float* ln0_g  = (const float*)d_in[4];
    const float* ln0_b  = (const float*)d_in[5];
    const float* sim_W1 = (const float*)d_in[6];
    const float* sim_b1 = (const float*)d_in[7];
    const float* sim_W2 = (const float*)d_in[8];
    const float* sim_b2 = (const float*)d_in[9];
    const float* W_msg  = (const float*)d_in[10];
    const float* W_upd  = (const float*)d_in[11];
    const float* b_upd  = (const float*)d_in[12];
    const float* ln_g   = (const float*)d_in[13];
    const float* ln_b   = (const float*)d_in[14];
    const float* cls_W1 = (const float*)d_in[15];
    const float* cls_b1 = (const float*)d_in[16];
    const float* cls_W2 = (const float*)d_in[17];
    const float* cls_b2 = (const float*)d_in[18];

    int N = in_sizes[0] / 256;
    int E = in_sizes[1] / 2;
    int L = in_sizes[6] / (3 * HD * HD);
    int Etot = E + N;
    const int* srcA = ei;
    const int* dstA = ei + E;

    float* ws = (float*)d_ws;
    size_t nh = (size_t)N * HD;
    float* h       = ws;
    float* pre_agg = h + nh;
    float* score   = pre_agg + nh;
    float* wcomb   = score + Etot + 64;                      // L * 256*128 floats
    unsigned short* w1bf = (unsigned short*)(wcomb + (size_t)L * 32768);
    int*   cnt    = (int*)(w1bf + (size_t)L * 49152);
    int*   rowptr = cnt + N;
    int*   cursor = rowptr + N + 1;
    int*   esrc   = cursor + N;
    int*   edst   = esrc + Etot;

    int gemm_blocks = (N + 31) / 32;

    // CSR build (edge_index constant across layers)
    hipMemsetAsync(cnt, 0, (size_t)N * sizeof(int), stream);
    hist_kernel<<<512, 256, 0, stream>>>(dstA, cnt, E, Etot);
    scan_kernel<<<1, 256, 0, stream>>>(cnt, rowptr, cursor, N, Etot);
    scatter_kernel<<<512, 256, 0, stream>>>(srcA, dstA, cursor, esrc, edst, E, Etot);

    // W1 -> bf16 fragment-major (all layers, once)
    int w1_total = L * 49152;
    w1bf_kernel<<<(w1_total + 255) / 256, 256, 0, stream>>>(sim_W1, w1bf, w1_total);

    // wcomb[l] = [ W_upd[l][0:128] ; W_msg[l] @ W_upd[l][128:256] ]
    int cp_total = L * 16384;
    copy_upd_kernel<<<(cp_total + 255) / 256, 256, 0, stream>>>(W_upd, wcomb, cp_total);
    for (int l = 0; l < L; l++) {
        gemm_rows_kernel<<<(128 + 31) / 32, 256, 0, stream>>>(
            W_msg + (size_t)l * 16384, 128, nullptr, 0,
            W_upd + (size_t)l * 32768 + 16384, nullptr, nullptr, nullptr, nullptr,
            wcomb + (size_t)l * 32768 + 16384, 128);
    }

    // h = relu(LN(x @ proj_W + b))
    gemm_rows_kernel<<<gemm_blocks, 256, 0, stream>>>(x, 256, x + 128, 256, proj_W, proj_b,
                                                      nullptr, ln0_g, ln0_b, h, N);

    int gather_blocks = (N + 3) / 4;          // 5000, divisible by 8
    for (int l = 0; l < L; l++) {
        // edge scores (CSR order)
        edge_mfma_kernel<<<1024, 256, 0, stream>>>(h, esrc, edst,
                                                   w1bf + (size_t)l * 49152, sim_b1 + l * HD,
                                                   sim_W2 + l * HD, sim_b2 + l, score, Etot);
        // pre_agg = segment_sum(score * h[src])
        gather_kernel<<<gather_blocks, 256, 0, stream>>>(rowptr, esrc, score, h, pre_agg, N);
        // h = relu(LN(h@Wu1 + pre_agg@(Wmsg@Wu2) + b + h))
        gemm_rows_kernel<<<gemm_blocks, 256, 0, stream>>>(h, 128, pre_agg, 128,
                                                          wcomb + (size_t)l * 32768,
                                                          b_upd + l * HD, h,
                                                          ln_g + l * HD, ln_b + l * HD, h, N);
    }
    cls_kernel<<<768, 256, 0, stream>>>(h, cls_W1, cls_b1, cls_W2, cls_b2, (float*)d_out, N);
}

// Round 10
// 582.135 us; speedup vs baseline: 1.7997x; 1.0617x over previous
//
#include <hip/hip_runtime.h>
#include <hip/hip_bf16.h>

#define HD 128
#define LN_EPS 1e-5f

typedef __attribute__((ext_vector_type(8))) short short8;
typedef __attribute__((ext_vector_type(4))) float f32x4;

__device__ __forceinline__ unsigned short f2bf(float f) {
    union { float f; unsigned u; } v; v.f = f;
    unsigned r = (v.u + 0x7fffu + ((v.u >> 16) & 1u)) >> 16;
    return (unsigned short)r;
}

__device__ __forceinline__ unsigned cvtpk(float lo, float hi) {
    unsigned r;
    asm("v_cvt_pk_bf16_f32 %0, %1, %2" : "=v"(r) : "v"(lo), "v"(hi));
    return r;
}
__device__ __forceinline__ unsigned cvtpk_abs(float lo, float hi) {
    unsigned r;
    asm("v_cvt_pk_bf16_f32 %0, abs(%1), abs(%2)" : "=v"(r) : "v"(lo), "v"(hi));
    return r;
}
// packed |a-b| on bf16 pairs -> packed bf16
__device__ __forceinline__ unsigned absd_bf2(unsigned a, unsigned b) {
    float alo = __uint_as_float(a << 16), ahi = __uint_as_float(a & 0xffff0000u);
    float blo = __uint_as_float(b << 16), bhi = __uint_as_float(b & 0xffff0000u);
    return cvtpk_abs(alo - blo, ahi - bhi);
}

__device__ __forceinline__ float wave_sum_all(float v) {
    #pragma unroll
    for (int o = 32; o > 0; o >>= 1) v += __shfl_xor(v, o);
    return v;
}

// ---------------- W1 (L x 384x128 f32) -> bf16 fragment-major, all layers
__global__ __launch_bounds__(256) void w1bf_kernel(
    const float* __restrict__ W1, unsigned short* __restrict__ out, int total)
{
    int idx = blockIdx.x * 256 + threadIdx.x;
    if (idx >= total) return;
    int lw  = idx / 49152;
    int rem = idx - lw * 49152;
    int j  = rem & 7;
    int c  = (rem >> 3) & 15;
    int ks = (rem >> 7) & 3;
    int ct = (rem >> 9) & 7;
    int q  = rem >> 12;
    out[idx] = f2bf(W1[(size_t)lw * 49152 + (size_t)(q * 32 + ks * 8 + j) * 128 + ct * 16 + c]);
}

// ---------------- copy W_upd[l][0:128] into wcomb[l][0:128]
__global__ __launch_bounds__(256) void copy_upd_kernel(
    const float* __restrict__ W_upd, float* __restrict__ wcomb, int total)
{
    int idx = blockIdx.x * 256 + threadIdx.x;
    if (idx >= total) return;
    int l = idx / 16384, r = idx - l * 16384;
    wcomb[(size_t)l * 32768 + r] = W_upd[(size_t)l * 32768 + r];
}

// ---------------- fp32 GEMM: out[N][128] = cat(in0,in1)[N][K] @ W[K][128] (+bias)(+res)
// optional fused LN+relu epilogue (g != nullptr); optional bf16 mirror store (out_bf).
__global__ __launch_bounds__(256) void gemm_rows_kernel(
    const float* __restrict__ in0, int s0, const float* __restrict__ in1, int s1,
    const float* __restrict__ W, const float* __restrict__ bias,
    const float* __restrict__ res, const float* __restrict__ g,
    const float* __restrict__ bln, float* __restrict__ out,
    unsigned* __restrict__ out_bf, int N)
{
    __shared__ __align__(16) float rows[4][8][256];
    int tid = threadIdx.x, wv = tid >> 6, lane = tid & 63;
    int rbase = (blockIdx.x * 4 + wv) * 8;
    if (rbase >= N) return;
    int K = in1 ? 256 : 128;
    int r = lane >> 3, seg = lane & 7;
    int row = min(rbase + r, N - 1);
    {
        const float4* p = (const float4*)(in0 + (size_t)row * s0 + seg * 16);
        float4* q = (float4*)&rows[wv][r][seg * 16];
        #pragma unroll
        for (int i = 0; i < 4; i++) q[i] = p[i];
        if (in1) {
            const float4* p1 = (const float4*)(in1 + (size_t)row * s1 + seg * 16);
            float4* q1 = (float4*)&rows[wv][r][128 + seg * 16];
            #pragma unroll
            for (int i = 0; i < 4; i++) q1[i] = p1[i];
        }
    }
    asm volatile("s_waitcnt lgkmcnt(0)" ::: "memory");
    float2 acc[8];
    float2 bv = make_float2(0.f, 0.f);
    if (bias) bv = *(const float2*)(bias + 2 * lane);
    #pragma unroll
    for (int t = 0; t < 8; t++) acc[t] = bv;
    for (int k = 0; k < K; k += 4) {
        float2 w0 = *(const float2*)(W + (size_t)(k + 0) * 128 + 2 * lane);
        float2 w1 = *(const float2*)(W + (size_t)(k + 1) * 128 + 2 * lane);
        float2 w2 = *(const float2*)(W + (size_t)(k + 2) * 128 + 2 * lane);
        float2 w3 = *(const float2*)(W + (size_t)(k + 3) * 128 + 2 * lane);
        #pragma unroll
        for (int t = 0; t < 8; t++) {
            float4 a = *(const float4*)&rows[wv][t][k];
            acc[t].x = fmaf(a.x, w0.x, acc[t].x); acc[t].y = fmaf(a.x, w0.y, acc[t].y);
            acc[t].x = fmaf(a.y, w1.x, acc[t].x); acc[t].y = fmaf(a.y, w1.y, acc[t].y);
            acc[t].x = fmaf(a.z, w2.x, acc[t].x); acc[t].y = fmaf(a.z, w2.y, acc[t].y);
            acc[t].x = fmaf(a.w, w3.x, acc[t].x); acc[t].y = fmaf(a.w, w3.y, acc[t].y);
        }
    }
    if (res) {
        #pragma unroll
        for (int t = 0; t < 8; t++) {
            int rw = rbase + t;
            if (rw < N) {
                float2 rv = *(const float2*)(res + (size_t)rw * 128 + 2 * lane);
                acc[t].x += rv.x; acc[t].y += rv.y;
            }
        }
    }
    if (g) {
        float2 gv = *(const float2*)(g + 2 * lane);
        float2 lv = *(const float2*)(bln + 2 * lane);
        #pragma unroll
        for (int t = 0; t < 8; t++) {
            int rw = rbase + t;
            if (rw >= N) break;
            float s  = wave_sum_all(acc[t].x + acc[t].y);
            float s2 = wave_sum_all(acc[t].x * acc[t].x + acc[t].y * acc[t].y);
            float mu = s * (1.f / 128.f);
            float var = s2 * (1.f / 128.f) - mu * mu;
            float rs = rsqrtf(var + LN_EPS);
            float2 y;
            y.x = fmaxf((acc[t].x - mu) * rs * gv.x + lv.x, 0.f);
            y.y = fmaxf((acc[t].y - mu) * rs * gv.y + lv.y, 0.f);
            *(float2*)(out + (size_t)rw * 128 + 2 * lane) = y;
            if (out_bf) out_bf[(size_t)rw * 64 + lane] = cvtpk(y.x, y.y);
        }
    } else {
        #pragma unroll
        for (int t = 0; t < 8; t++) {
            int rw = rbase + t;
            if (rw < N) *(float2*)(out + (size_t)rw * 128 + 2 * lane) = acc[t];
        }
    }
}

// ---------------- CSR build ----------------
__global__ __launch_bounds__(256) void hist_kernel(
    const int* __restrict__ dstA, int* __restrict__ cnt, int E, int Etot)
{
    for (int e = blockIdx.x * 256 + threadIdx.x; e < Etot; e += gridDim.x * 256) {
        int di = (e < E) ? dstA[e] : (e - E);
        atomicAdd(&cnt[di], 1);
    }
}

__global__ __launch_bounds__(256) void scan_kernel(
    const int* __restrict__ cnt, int* __restrict__ rowptr, int* __restrict__ cursor,
    int N, int Etot)
{
    __shared__ int ls[256];
    int t = threadIdx.x;
    int chunk = (N + 255) / 256;
    int lo = t * chunk, hi = min(lo + chunk, N);
    int s = 0;
    for (int i = lo; i < hi; i++) s += cnt[i];
    ls[t] = s;
    __syncthreads();
    for (int off = 1; off < 256; off <<= 1) {
        int v = (t >= off) ? ls[t - off] : 0;
        __syncthreads();
        ls[t] += v;
        __syncthreads();
    }
    int run = ls[t] - s;
    for (int i = lo; i < hi; i++) {
        rowptr[i] = run; cursor[i] = run;
        run += cnt[i];
    }
    if (t == 0) rowptr[N] = Etot;
}

__global__ __launch_bounds__(256) void scatter_kernel(
    const int* __restrict__ srcA, const int* __restrict__ dstA,
    int* __restrict__ cursor, int* __restrict__ esrc, int* __restrict__ edst,
    int E, int Etot)
{
    for (int e = blockIdx.x * 256 + threadIdx.x; e < Etot; e += gridDim.x * 256) {
        int si = (e < E) ? srcA[e] : (e - E);
        int di = (e < E) ? dstA[e] : (e - E);
        int pos = atomicAdd(&cursor[di], 1);
        esrc[pos] = si;
        edst[pos] = di;
    }
}

// ---------------- edge scores via MFMA (CSR order), bf16 h source
// planes: xi +0, xj +16384, d +32768 (plane = 64 rows x 256 B, XOR swizzle)
__global__ __launch_bounds__(256) void edge_mfma_kernel(
    const unsigned* __restrict__ hbf,
    const int* __restrict__ esrc, const int* __restrict__ edst,
    const unsigned short* __restrict__ w1bf, const float* __restrict__ b1,
    const float* __restrict__ W2, const float* __restrict__ b2p,
    float* __restrict__ score, int Etot)
{
    __shared__ __align__(16) short sim[3][64][128];   // 48 KB
    __shared__ float pl[4][64];
    int tid = threadIdx.x, wv = tid >> 6, lane = tid & 63;
    char* simb = (char*)sim;

    short8 wf[12][2];
    {
        int ks = lane >> 4, c = lane & 15;
        #pragma unroll
        for (int q = 0; q < 12; q++)
            #pragma unroll
            for (int n = 0; n < 2; n++) {
                int ct = wv * 2 + n;
                wf[q][n] = *(const short8*)(w1bf + (size_t)(((q * 8 + ct) * 4 + ks) * 128 + c * 8));
            }
    }
    float b1x = b1[wv * 32 + (lane & 15)],  b1y = b1[wv * 32 + 16 + (lane & 15)];
    float w2x = W2[wv * 32 + (lane & 15)],  w2y = W2[wv * 32 + 16 + (lane & 15)];
    float b2 = b2p[0];

    int nb = gridDim.x;
    int swz = (blockIdx.x & 7) * (nb >> 3) + (blockIdx.x >> 3);
    int ntiles = (Etot + 63) >> 6;
    int t0 = (int)(((long long)ntiles * swz) / nb);
    int t1 = (int)(((long long)ntiles * (swz + 1)) / nb);

    for (int tile = t0; tile < t1; tile++) {
        int ebase = tile << 6;
        {
            int el = tid >> 2, seg = tid & 3;
            int e = ebase + el; if (e >= Etot) e = Etot - 1;
            int si = esrc[e];
            int di = edst[e];
            const uint4* xi = (const uint4*)(hbf + (size_t)di * 64 + seg * 16);
            const uint4* xj = (const uint4*)(hbf + (size_t)si * 64 + seg * 16);
            int rowoff = el * 256, sw = (el & 7) << 4;
            #pragma unroll
            for (int i = 0; i < 4; i++) {
                uint4 a = xi[i], b = xj[i];
                uint4 d;
                d.x = absd_bf2(a.x, b.x); d.y = absd_bf2(a.y, b.y);
                d.z = absd_bf2(a.z, b.z); d.w = absd_bf2(a.w, b.w);
                int off = rowoff + ((seg * 64 + i * 16) ^ sw);
                *(uint4*)(simb + off)         = a;
                *(uint4*)(simb + 16384 + off) = b;
                *(uint4*)(simb + 32768 + off) = d;
            }
        }
        __syncthreads();
        f32x4 acc[4][2];
        #pragma unroll
        for (int m = 0; m < 4; m++)
            #pragma unroll
            for (int n = 0; n < 2; n++)
                #pragma unroll
                for (int r = 0; r < 4; r++) acc[m][n][r] = 0.f;
        #pragma unroll
        for (int q = 0; q < 12; q++) {
            int third = q >> 2;
            int kin = ((q & 3) * 64 + (lane >> 4) * 16);
            short8 af[4];
            #pragma unroll
            for (int m = 0; m < 4; m++) {
                int el = m * 16 + (lane & 15);
                int addr = third * 16384 + el * 256 + (kin ^ ((el & 7) << 4));
                af[m] = *(const short8*)(simb + addr);
            }
            #pragma unroll
            for (int m = 0; m < 4; m++)
                #pragma unroll
                for (int n = 0; n < 2; n++)
                    acc[m][n] = __builtin_amdgcn_mfma_f32_16x16x32_bf16(af[m], wf[q][n], acc[m][n], 0, 0, 0);
        }
        #pragma unroll
        for (int m = 0; m < 4; m++) {
            #pragma unroll
            for (int r = 0; r < 4; r++) {
                float v = fmaxf(acc[m][0][r] + b1x, 0.f) * w2x
                        + fmaxf(acc[m][1][r] + b1y, 0.f) * w2y;
                v += __shfl_xor(v, 1); v += __shfl_xor(v, 2);
                v += __shfl_xor(v, 4); v += __shfl_xor(v, 8);
                if ((lane & 15) == 0) pl[wv][m * 16 + (lane >> 4) * 4 + r] = v;
            }
        }
        __syncthreads();
        if (tid < 64) {
            int e = ebase + tid;
            if (e < Etot) {
                float z = pl[0][tid] + pl[1][tid] + pl[2][tid] + pl[3][tid] + b2;
                score[e] = 1.f / (1.f + __expf(-z));
            }
        }
        // no trailing barrier: next tile's pl writes are gated by its own post-staging barrier,
        // which wave 0 only reaches after finishing the score writes above.
    }
}

// ---------------- pre_agg[n] = sum score[pos]*hbf[esrc[pos]]  (fp32 accum)
__global__ __launch_bounds__(256) void gather_kernel(
    const int* __restrict__ rowptr, const int* __restrict__ esrc,
    const float* __restrict__ score, const unsigned* __restrict__ hbf,
    float* __restrict__ pre_agg, int N)
{
    int nb = gridDim.x;
    int bid = blockIdx.x;
    int swz = (bid & 7) * (nb >> 3) + (bid >> 3);
    int wvi = threadIdx.x >> 6, lane = threadIdx.x & 63;
    int node = swz * 4 + wvi;
    if (node >= N) return;
    int p0 = rowptr[node], p1 = rowptr[node + 1];
    float2 a0 = make_float2(0.f, 0.f), a1 = a0, a2 = a0, a3 = a0;
    for (int base = p0; base < p1; base += 64) {
        int cnt = min(64, p1 - base);
        int sidx = 0; float sc = 0.f;
        if (lane < cnt) {
            sidx = esrc[base + lane];
            sc = score[base + lane];
        }
        int i = 0;
        for (; i + 4 <= cnt; i += 4) {
            float s0 = __shfl(sc, i),     s1 = __shfl(sc, i + 1);
            float s2 = __shfl(sc, i + 2), s3 = __shfl(sc, i + 3);
            int r0 = __shfl(sidx, i),     r1 = __shfl(sidx, i + 1);
            int r2 = __shfl(sidx, i + 2), r3 = __shfl(sidx, i + 3);
            unsigned u0 = hbf[(size_t)r0 * 64 + lane];
            unsigned u1 = hbf[(size_t)r1 * 64 + lane];
            unsigned u2 = hbf[(size_t)r2 * 64 + lane];
            unsigned u3 = hbf[(size_t)r3 * 64 + lane];
            a0.x = fmaf(s0, __uint_as_float(u0 << 16), a0.x);
            a0.y = fmaf(s0, __uint_as_float(u0 & 0xffff0000u), a0.y);
            a1.x = fmaf(s1, __uint_as_float(u1 << 16), a1.x);
            a1.y = fmaf(s1, __uint_as_float(u1 & 0xffff0000u), a1.y);
            a2.x = fmaf(s2, __uint_as_float(u2 << 16), a2.x);
            a2.y = fmaf(s2, __uint_as_float(u2 & 0xffff0000u), a2.y);
            a3.x = fmaf(s3, __uint_as_float(u3 << 16), a3.x);
            a3.y = fmaf(s3, __uint_as_float(u3 & 0xffff0000u), a3.y);
        }
        for (; i < cnt; i++) {
            float s = __shfl(sc, i);
            int rr = __shfl(sidx, i);
            unsigned u = hbf[(size_t)rr * 64 + lane];
            a0.x = fmaf(s, __uint_as_float(u << 16), a0.x);
            a0.y = fmaf(s, __uint_as_float(u & 0xffff0000u), a0.y);
        }
    }
    float2 o;
    o.x = (a0.x + a1.x) + (a2.x + a3.x);
    o.y = (a0.y + a1.y) + (a2.y + a3.y);
    *(float2*)(pre_agg + (size_t)node * 128 + 2 * lane) = o;
}

// ---------------- classifier
__global__ __launch_bounds__(256) void cls_kernel(
    const float* __restrict__ hin, const float* __restrict__ W1,
    const float* __restrict__ b1, const float* __restrict__ W2,
    const float* __restrict__ b2, float* __restrict__ out, int N)
{
    __shared__ __align__(16) float w1[HD * 64];
    __shared__ __align__(16) float w2[64 * 40];
    __shared__ __align__(16) float hs[4][HD];
    __shared__ float ts[4][64];
    for (int i = threadIdx.x; i < HD * 64; i += 256) w1[i] = W1[i];
    for (int i = threadIdx.x; i < 64 * 40; i += 256) w2[i] = W2[i];
    int sub = threadIdx.x >> 6, t = threadIdx.x & 63;
    float b1j = b1[t];
    float b2j = (t < 40) ? b2[t] : 0.f;
    __syncthreads();
    for (int base = blockIdx.x * 4; base < N; base += gridDim.x * 4) {
        int i = base + sub; bool val = i < N;
        if (val) { hs[sub][t] = hin[(size_t)i * HD + t]; hs[sub][64 + t] = hin[(size_t)i * HD + 64 + t]; }
        __syncthreads();
        float acc = b1j;
        const float* hr = hs[sub];
        #pragma unroll 8
        for (int k = 0; k < HD; k += 4) {
            float4 hv = *(const float4*)(hr + k);
            acc = fmaf(hv.x, w1[(k + 0) * 64 + t], acc);
            acc = fmaf(hv.y, w1[(k + 1) * 64 + t], acc);
            acc = fmaf(hv.z, w1[(k + 2) * 64 + t], acc);
            acc = fmaf(hv.w, w1[(k + 3) * 64 + t], acc);
        }
        ts[sub][t] = fmaxf(acc, 0.f);
        __syncthreads();
        if (val && t < 40) {
            float o = b2j;
            const float* tr = ts[sub];
            #pragma unroll 8
            for (int k = 0; k < 64; k++) o = fmaf(tr[k], w2[k * 40 + t], o);
            out[(size_t)i * 40 + t] = o;
        }
        __syncthreads();
    }
}

extern "C" void kernel_launch(void* const* d_in, const int* in_sizes, int n_in,
                              void* d_out, int out_size, void* d_ws, size_t ws_size,
                              hipStream_t stream)
{
    const float* x      = (const float*)d_in[0];
    const int*   ei     = (const int*)d_in[1];
    const float* proj_W = (const float*)d_in[2];
    const float* proj_b = (const float*)d_in[3];
    const float* ln0_g  = (const float*)d_in[4];
    const float* ln0_b  = (const float*)d_in[5];
    const float* sim_W1 = (const float*)d_in[6];
    const float* sim_b1 = (const float*)d_in[7];
    const float* sim_W2 = (const float*)d_in[8];
    const float* sim_b2 = (const float*)d_in[9];
    const float* W_msg  = (const float*)d_in[10];
    const float* W_upd  = (const float*)d_in[11];
    const float* b_upd  = (const float*)d_in[12];
    const float* ln_g   = (const float*)d_in[13];
    const float* ln_b   = (const float*)d_in[14];
    const float* cls_W1 = (const float*)d_in[15];
    const float* cls_b1 = (const float*)d_in[16];
    const float* cls_W2 = (const float*)d_in[17];
    const float* cls_b2 = (const float*)d_in[18];

    int N = in_sizes[0] / 256;
    int E = in_sizes[1] / 2;
    int L = in_sizes[6] / (3 * HD * HD);
    int Etot = E + N;
    const int* srcA = ei;
    const int* dstA = ei + E;

    float* ws = (float*)d_ws;
    size_t nh = (size_t)N * HD;
    float* h       = ws;
    float* pre_agg = h + nh;
    float* score   = pre_agg + nh;
    float* wcomb   = score + Etot + 64;                      // L * 256*128 floats
    unsigned* hbf  = (unsigned*)(wcomb + (size_t)L * 32768); // N*64 uints
    unsigned short* w1bf = (unsigned short*)(hbf + nh / 2);
    int*   cnt    = (int*)(w1bf + (size_t)L * 49152);
    int*   rowptr = cnt + N;
    int*   cursor = rowptr + N + 1;
    int*   esrc   = cursor + N;
    int*   edst   = esrc + Etot;

    int gemm_blocks = (N + 31) / 32;

    // CSR build (edge_index constant across layers)
    hipMemsetAsync(cnt, 0, (size_t)N * sizeof(int), stream);
    hist_kernel<<<512, 256, 0, stream>>>(dstA, cnt, E, Etot);
    scan_kernel<<<1, 256, 0, stream>>>(cnt, rowptr, cursor, N, Etot);
    scatter_kernel<<<512, 256, 0, stream>>>(srcA, dstA, cursor, esrc, edst, E, Etot);

    // W1 -> bf16 fragment-major (all layers, once)
    int w1_total = L * 49152;
    w1bf_kernel<<<(w1_total + 255) / 256, 256, 0, stream>>>(sim_W1, w1bf, w1_total);

    // wcomb[l] = [ W_upd[l][0:128] ; W_msg[l] @ W_upd[l][128:256] ]
    int cp_total = L * 16384;
    copy_upd_kernel<<<(cp_total + 255) / 256, 256, 0, stream>>>(W_upd, wcomb, cp_total);
    for (int l = 0; l < L; l++) {
        gemm_rows_kernel<<<(128 + 31) / 32, 256, 0, stream>>>(
            W_msg + (size_t)l * 16384, 128, nullptr, 0,
            W_upd + (size_t)l * 32768 + 16384, nullptr, nullptr, nullptr, nullptr,
            wcomb + (size_t)l * 32768 + 16384, nullptr, 128);
    }

    // h = relu(LN(x @ proj_W + b)), hbf mirror
    gemm_rows_kernel<<<gemm_blocks, 256, 0, stream>>>(x, 256, x + 128, 256, proj_W, proj_b,
                                                      nullptr, ln0_g, ln0_b, h, hbf, N);

    int gather_blocks = (N + 3) / 4;          // 5000, divisible by 8
    for (int l = 0; l < L; l++) {
        edge_mfma_kernel<<<768, 256, 0, stream>>>(hbf, esrc, edst,
                                                  w1bf + (size_t)l * 49152, sim_b1 + l * HD,
                                                  sim_W2 + l * HD, sim_b2 + l, score, Etot);
        gather_kernel<<<gather_blocks, 256, 0, stream>>>(rowptr, esrc, score, hbf, pre_agg, N);
        gemm_rows_kernel<<<gemm_blocks, 256, 0, stream>>>(h, 128, pre_agg, 128,
                                                          wcomb + (size_t)l * 32768,
                                                          b_upd + l * HD, h,
                                                          ln_g + l * HD, ln_b + l * HD, h, hbf, N);
    }
    cls_kernel<<<768, 256, 0, stream>>>(h, cls_W1, cls_b1, cls_W2, cls_b2, (float*)d_out, N);
}

// Round 11
// 488.356 us; speedup vs baseline: 2.1453x; 1.1920x over previous
//
#include <hip/hip_runtime.h>
#include <hip/hip_bf16.h>

#define HD 128
#define LN_EPS 1e-5f

typedef __attribute__((ext_vector_type(8))) short short8;
typedef __attribute__((ext_vector_type(4))) float f32x4;

__device__ __forceinline__ unsigned short f2bf(float f) {
    union { float f; unsigned u; } v; v.f = f;
    unsigned r = (v.u + 0x7fffu + ((v.u >> 16) & 1u)) >> 16;
    return (unsigned short)r;
}

__device__ __forceinline__ unsigned cvtpk(float lo, float hi) {
    unsigned r;
    asm("v_cvt_pk_bf16_f32 %0, %1, %2" : "=v"(r) : "v"(lo), "v"(hi));
    return r;
}
__device__ __forceinline__ unsigned cvtpk_abs(float lo, float hi) {
    unsigned r;
    asm("v_cvt_pk_bf16_f32 %0, abs(%1), abs(%2)" : "=v"(r) : "v"(lo), "v"(hi));
    return r;
}
// packed |a-b| on bf16 pairs -> packed bf16
__device__ __forceinline__ unsigned absd_bf2(unsigned a, unsigned b) {
    float alo = __uint_as_float(a << 16), ahi = __uint_as_float(a & 0xffff0000u);
    float blo = __uint_as_float(b << 16), bhi = __uint_as_float(b & 0xffff0000u);
    return cvtpk_abs(alo - blo, ahi - bhi);
}

__device__ __forceinline__ float wave_sum_all(float v) {
    #pragma unroll
    for (int o = 32; o > 0; o >>= 1) v += __shfl_xor(v, o);
    return v;
}

// ---------------- W1 (L x 384x128 f32) -> bf16 fragment-major, all layers
__global__ __launch_bounds__(256) void w1bf_kernel(
    const float* __restrict__ W1, unsigned short* __restrict__ out, int total)
{
    int idx = blockIdx.x * 256 + threadIdx.x;
    if (idx >= total) return;
    int lw  = idx / 49152;
    int rem = idx - lw * 49152;
    int j  = rem & 7;
    int c  = (rem >> 3) & 15;
    int ks = (rem >> 7) & 3;
    int ct = (rem >> 9) & 7;
    int q  = rem >> 12;
    out[idx] = f2bf(W1[(size_t)lw * 49152 + (size_t)(q * 32 + ks * 8 + j) * 128 + ct * 16 + c]);
}

// ---------------- copy W_upd[l][0:128] into wcomb[l][0:128]
__global__ __launch_bounds__(256) void copy_upd_kernel(
    const float* __restrict__ W_upd, float* __restrict__ wcomb, int total)
{
    int idx = blockIdx.x * 256 + threadIdx.x;
    if (idx >= total) return;
    int l = idx / 16384, r = idx - l * 16384;
    wcomb[(size_t)l * 32768 + r] = W_upd[(size_t)l * 32768 + r];
}

// ---------------- fp32 GEMM: out[N][128] = cat(in0,in1)[N][K] @ W[K][128] (+bias)(+res)
// optional fused LN+relu epilogue (g != nullptr); optional bf16 mirror store (out_bf).
__global__ __launch_bounds__(256) void gemm_rows_kernel(
    const float* __restrict__ in0, int s0, const float* __restrict__ in1, int s1,
    const float* __restrict__ W, const float* __restrict__ bias,
    const float* __restrict__ res, const float* __restrict__ g,
    const float* __restrict__ bln, float* __restrict__ out,
    unsigned* __restrict__ out_bf, int N)
{
    __shared__ __align__(16) float rows[4][8][256];
    int tid = threadIdx.x, wv = tid >> 6, lane = tid & 63;
    int rbase = (blockIdx.x * 4 + wv) * 8;
    if (rbase >= N) return;
    int K = in1 ? 256 : 128;
    int r = lane >> 3, seg = lane & 7;
    int row = min(rbase + r, N - 1);
    {
        const float4* p = (const float4*)(in0 + (size_t)row * s0 + seg * 16);
        float4* q = (float4*)&rows[wv][r][seg * 16];
        #pragma unroll
        for (int i = 0; i < 4; i++) q[i] = p[i];
        if (in1) {
            const float4* p1 = (const float4*)(in1 + (size_t)row * s1 + seg * 16);
            float4* q1 = (float4*)&rows[wv][r][128 + seg * 16];
            #pragma unroll
            for (int i = 0; i < 4; i++) q1[i] = p1[i];
        }
    }
    asm volatile("s_waitcnt lgkmcnt(0)" ::: "memory");
    float2 acc[8];
    float2 bv = make_float2(0.f, 0.f);
    if (bias) bv = *(const float2*)(bias + 2 * lane);
    #pragma unroll
    for (int t = 0; t < 8; t++) acc[t] = bv;
    for (int k = 0; k < K; k += 4) {
        float2 w0 = *(const float2*)(W + (size_t)(k + 0) * 128 + 2 * lane);
        float2 w1 = *(const float2*)(W + (size_t)(k + 1) * 128 + 2 * lane);
        float2 w2 = *(const float2*)(W + (size_t)(k + 2) * 128 + 2 * lane);
        float2 w3 = *(const float2*)(W + (size_t)(k + 3) * 128 + 2 * lane);
        #pragma unroll
        for (int t = 0; t < 8; t++) {
            float4 a = *(const float4*)&rows[wv][t][k];
            acc[t].x = fmaf(a.x, w0.x, acc[t].x); acc[t].y = fmaf(a.x, w0.y, acc[t].y);
            acc[t].x = fmaf(a.y, w1.x, acc[t].x); acc[t].y = fmaf(a.y, w1.y, acc[t].y);
            acc[t].x = fmaf(a.z, w2.x, acc[t].x); acc[t].y = fmaf(a.z, w2.y, acc[t].y);
            acc[t].x = fmaf(a.w, w3.x, acc[t].x); acc[t].y = fmaf(a.w, w3.y, acc[t].y);
        }
    }
    if (res) {
        #pragma unroll
        for (int t = 0; t < 8; t++) {
            int rw = rbase + t;
            if (rw < N) {
                float2 rv = *(const float2*)(res + (size_t)rw * 128 + 2 * lane);
                acc[t].x += rv.x; acc[t].y += rv.y;
            }
        }
    }
    if (g) {
        float2 gv = *(const float2*)(g + 2 * lane);
        float2 lv = *(const float2*)(bln + 2 * lane);
        #pragma unroll
        for (int t = 0; t < 8; t++) {
            int rw = rbase + t;
            if (rw >= N) break;
            float s  = wave_sum_all(acc[t].x + acc[t].y);
            float s2 = wave_sum_all(acc[t].x * acc[t].x + acc[t].y * acc[t].y);
            float mu = s * (1.f / 128.f);
            float var = s2 * (1.f / 128.f) - mu * mu;
            float rs = rsqrtf(var + LN_EPS);
            float2 y;
            y.x = fmaxf((acc[t].x - mu) * rs * gv.x + lv.x, 0.f);
            y.y = fmaxf((acc[t].y - mu) * rs * gv.y + lv.y, 0.f);
            *(float2*)(out + (size_t)rw * 128 + 2 * lane) = y;
            if (out_bf) out_bf[(size_t)rw * 64 + lane] = cvtpk(y.x, y.y);
        }
    } else {
        #pragma unroll
        for (int t = 0; t < 8; t++) {
            int rw = rbase + t;
            if (rw < N) *(float2*)(out + (size_t)rw * 128 + 2 * lane) = acc[t];
        }
    }
}

// ---------------- CSR build ----------------
__global__ __launch_bounds__(256) void hist_kernel(
    const int* __restrict__ dstA, int* __restrict__ cnt, int E, int Etot)
{
    for (int e = blockIdx.x * 256 + threadIdx.x; e < Etot; e += gridDim.x * 256) {
        int di = (e < E) ? dstA[e] : (e - E);
        atomicAdd(&cnt[di], 1);
    }
}

__global__ __launch_bounds__(256) void scan_kernel(
    const int* __restrict__ cnt, int* __restrict__ rowptr, int* __restrict__ cursor,
    int N, int Etot)
{
    __shared__ int ls[256];
    int t = threadIdx.x;
    int chunk = (N + 255) / 256;
    int lo = t * chunk, hi = min(lo + chunk, N);
    int s = 0;
    for (int i = lo; i < hi; i++) s += cnt[i];
    ls[t] = s;
    __syncthreads();
    for (int off = 1; off < 256; off <<= 1) {
        int v = (t >= off) ? ls[t - off] : 0;
        __syncthreads();
        ls[t] += v;
        __syncthreads();
    }
    int run = ls[t] - s;
    for (int i = lo; i < hi; i++) {
        rowptr[i] = run; cursor[i] = run;
        run += cnt[i];
    }
    if (t == 0) rowptr[N] = Etot;
}

__global__ __launch_bounds__(256) void scatter_kernel(
    const int* __restrict__ srcA, const int* __restrict__ dstA,
    int* __restrict__ cursor, int* __restrict__ esrc, int* __restrict__ edst,
    int E, int Etot)
{
    for (int e = blockIdx.x * 256 + threadIdx.x; e < Etot; e += gridDim.x * 256) {
        int si = (e < E) ? srcA[e] : (e - E);
        int di = (e < E) ? dstA[e] : (e - E);
        int pos = atomicAdd(&cursor[di], 1);
        esrc[pos] = si;
        edst[pos] = di;
    }
}

// ---------------- edge scores via MFMA (CSR order), bf16 h source
// planes: xi +0, xj +16384, d +32768 (plane = 64 rows x 256 B, XOR swizzle)
// __launch_bounds__(256,3): 3 waves/SIMD is the real (LDS-capped) occupancy ->
// gives the regalloc a 170-VGPR budget so the 8 staging loads stay in flight.
__global__ __launch_bounds__(256, 3) void edge_mfma_kernel(
    const unsigned* __restrict__ hbf,
    const int* __restrict__ esrc, const int* __restrict__ edst,
    const unsigned short* __restrict__ w1bf, const float* __restrict__ b1,
    const float* __restrict__ W2, const float* __restrict__ b2p,
    float* __restrict__ score, int Etot)
{
    __shared__ __align__(16) short sim[3][64][128];   // 48 KB
    __shared__ float pl[4][64];
    int tid = threadIdx.x, wv = tid >> 6, lane = tid & 63;
    char* simb = (char*)sim;

    short8 wf[12][2];
    {
        int ks = lane >> 4, c = lane & 15;
        #pragma unroll
        for (int q = 0; q < 12; q++)
            #pragma unroll
            for (int n = 0; n < 2; n++) {
                int ct = wv * 2 + n;
                wf[q][n] = *(const short8*)(w1bf + (size_t)(((q * 8 + ct) * 4 + ks) * 128 + c * 8));
            }
    }
    float b1x = b1[wv * 32 + (lane & 15)],  b1y = b1[wv * 32 + 16 + (lane & 15)];
    float w2x = W2[wv * 32 + (lane & 15)],  w2y = W2[wv * 32 + 16 + (lane & 15)];
    float b2 = b2p[0];

    int nb = gridDim.x;
    int swz = (blockIdx.x & 7) * (nb >> 3) + (blockIdx.x >> 3);
    int ntiles = (Etot + 63) >> 6;
    int t0 = (int)(((long long)ntiles * swz) / nb);
    int t1 = (int)(((long long)ntiles * (swz + 1)) / nb);
    if (t0 >= t1) return;

    int el = tid >> 2, seg = tid & 3;
    // prefetched indices for the current tile
    int e_cur = min((t0 << 6) + el, Etot - 1);
    int si = esrc[e_cur];
    int di = edst[e_cur];

    for (int tile = t0; tile < t1; tile++) {
        // ---- stage: all 8 row loads issued upfront (batched, no load-use interleave)
        const uint4* xi = (const uint4*)(hbf + (size_t)di * 64 + seg * 16);
        const uint4* xj = (const uint4*)(hbf + (size_t)si * 64 + seg * 16);
        uint4 a0 = xi[0], b0 = xj[0];
        uint4 a1 = xi[1], b1v = xj[1];
        uint4 a2 = xi[2], b2v = xj[2];
        uint4 a3 = xi[3], b3v = xj[3];
        // prefetch next tile's indices (breaks idx->row dependency chain)
        {
            int nt = (tile + 1 < t1) ? (tile + 1) : tile;
            int en = min((nt << 6) + el, Etot - 1);
            si = esrc[en];
            di = edst[en];
        }
        {
            int rowoff = el * 256, sw = (el & 7) << 4;
            uint4 d0, d1, d2, d3;
            d0.x = absd_bf2(a0.x, b0.x); d0.y = absd_bf2(a0.y, b0.y);
            d0.z = absd_bf2(a0.z, b0.z); d0.w = absd_bf2(a0.w, b0.w);
            d1.x = absd_bf2(a1.x, b1v.x); d1.y = absd_bf2(a1.y, b1v.y);
            d1.z = absd_bf2(a1.z, b1v.z); d1.w = absd_bf2(a1.w, b1v.w);
            d2.x = absd_bf2(a2.x, b2v.x); d2.y = absd_bf2(a2.y, b2v.y);
            d2.z = absd_bf2(a2.z, b2v.z); d2.w = absd_bf2(a2.w, b2v.w);
            d3.x = absd_bf2(a3.x, b3v.x); d3.y = absd_bf2(a3.y, b3v.y);
            d3.z = absd_bf2(a3.z, b3v.z); d3.w = absd_bf2(a3.w, b3v.w);
            int o0 = rowoff + ((seg * 64 +  0) ^ sw);
            int o1 = rowoff + ((seg * 64 + 16) ^ sw);
            int o2 = rowoff + ((seg * 64 + 32) ^ sw);
            int o3 = rowoff + ((seg * 64 + 48) ^ sw);
            *(uint4*)(simb + o0)         = a0;  *(uint4*)(simb + o1)         = a1;
            *(uint4*)(simb + o2)         = a2;  *(uint4*)(simb + o3)         = a3;
            *(uint4*)(simb + 16384 + o0) = b0;  *(uint4*)(simb + 16384 + o1) = b1v;
            *(uint4*)(simb + 16384 + o2) = b2v; *(uint4*)(simb + 16384 + o3) = b3v;
            *(uint4*)(simb + 32768 + o0) = d0;  *(uint4*)(simb + 32768 + o1) = d1;
            *(uint4*)(simb + 32768 + o2) = d2;  *(uint4*)(simb + 32768 + o3) = d3;
        }
        __syncthreads();
        // ---- MFMA: C[64 edges][32 cols] per wave
        f32x4 acc[4][2];
        #pragma unroll
        for (int m = 0; m < 4; m++)
            #pragma unroll
            for (int n = 0; n < 2; n++)
                #pragma unroll
                for (int r = 0; r < 4; r++) acc[m][n][r] = 0.f;
        __builtin_amdgcn_s_setprio(1);
        #pragma unroll
        for (int q = 0; q < 12; q++) {
            int third = q >> 2;
            int kin = ((q & 3) * 64 + (lane >> 4) * 16);
            short8 af[4];
            #pragma unroll
            for (int m = 0; m < 4; m++) {
                int elr = m * 16 + (lane & 15);
                int addr = third * 16384 + elr * 256 + (kin ^ ((elr & 7) << 4));
                af[m] = *(const short8*)(simb + addr);
            }
            #pragma unroll
            for (int m = 0; m < 4; m++)
                #pragma unroll
                for (int n = 0; n < 2; n++)
                    acc[m][n] = __builtin_amdgcn_mfma_f32_16x16x32_bf16(af[m], wf[q][n], acc[m][n], 0, 0, 0);
        }
        __builtin_amdgcn_s_setprio(0);
        int ebase = tile << 6;
        #pragma unroll
        for (int m = 0; m < 4; m++) {
            #pragma unroll
            for (int r = 0; r < 4; r++) {
                float v = fmaxf(acc[m][0][r] + b1x, 0.f) * w2x
                        + fmaxf(acc[m][1][r] + b1y, 0.f) * w2y;
                v += __shfl_xor(v, 1); v += __shfl_xor(v, 2);
                v += __shfl_xor(v, 4); v += __shfl_xor(v, 8);
                if ((lane & 15) == 0) pl[wv][m * 16 + (lane >> 4) * 4 + r] = v;
            }
        }
        __syncthreads();
        if (tid < 64) {
            int e = ebase + tid;
            if (e < Etot) {
                float z = pl[0][tid] + pl[1][tid] + pl[2][tid] + pl[3][tid] + b2;
                score[e] = 1.f / (1.f + __expf(-z));
            }
        }
        // no trailing barrier: next tile's pl writes are gated by its own post-staging barrier
    }
}

// ---------------- pre_agg[n] = sum score[pos]*hbf[esrc[pos]]  (fp32 accum)
__global__ __launch_bounds__(256) void gather_kernel(
    const int* __restrict__ rowptr, const int* __restrict__ esrc,
    const float* __restrict__ score, const unsigned* __restrict__ hbf,
    float* __restrict__ pre_agg, int N)
{
    int nb = gridDim.x;
    int bid = blockIdx.x;
    int swz = (bid & 7) * (nb >> 3) + (bid >> 3);
    int wvi = threadIdx.x >> 6, lane = threadIdx.x & 63;
    int node = swz * 4 + wvi;
    if (node >= N) return;
    int p0 = rowptr[node], p1 = rowptr[node + 1];
    float2 a0 = make_float2(0.f, 0.f), a1 = a0, a2 = a0, a3 = a0;
    for (int base = p0; base < p1; base += 64) {
        int cnt = min(64, p1 - base);
        int sidx = 0; float sc = 0.f;
        if (lane < cnt) {
            sidx = esrc[base + lane];
            sc = score[base + lane];
        }
        int i = 0;
        for (; i + 4 <= cnt; i += 4) {
            float s0 = __shfl(sc, i),     s1 = __shfl(sc, i + 1);
            float s2 = __shfl(sc, i + 2), s3 = __shfl(sc, i + 3);
            int r0 = __shfl(sidx, i),     r1 = __shfl(sidx, i + 1);
            int r2 = __shfl(sidx, i + 2), r3 = __shfl(sidx, i + 3);
            unsigned u0 = hbf[(size_t)r0 * 64 + lane];
            unsigned u1 = hbf[(size_t)r1 * 64 + lane];
            unsigned u2 = hbf[(size_t)r2 * 64 + lane];
            unsigned u3 = hbf[(size_t)r3 * 64 + lane];
            a0.x = fmaf(s0, __uint_as_float(u0 << 16), a0.x);
            a0.y = fmaf(s0, __uint_as_float(u0 & 0xffff0000u), a0.y);
            a1.x = fmaf(s1, __uint_as_float(u1 << 16), a1.x);
            a1.y = fmaf(s1, __uint_as_float(u1 & 0xffff0000u), a1.y);
            a2.x = fmaf(s2, __uint_as_float(u2 << 16), a2.x);
            a2.y = fmaf(s2, __uint_as_float(u2 & 0xffff0000u), a2.y);
            a3.x = fmaf(s3, __uint_as_float(u3 << 16), a3.x);
            a3.y = fmaf(s3, __uint_as_float(u3 & 0xffff0000u), a3.y);
        }
        for (; i < cnt; i++) {
            float s = __shfl(sc, i);
            int rr = __shfl(sidx, i);
            unsigned u = hbf[(size_t)rr * 64 + lane];
            a0.x = fmaf(s, __uint_as_float(u << 16), a0.x);
            a0.y = fmaf(s, __uint_as_float(u & 0xffff0000u), a0.y);
        }
    }
    float2 o;
    o.x = (a0.x + a1.x) + (a2.x + a3.x);
    o.y = (a0.y + a1.y) + (a2.y + a3.y);
    *(float2*)(pre_agg + (size_t)node * 128 + 2 * lane) = o;
}

// ---------------- classifier
__global__ __launch_bounds__(256) void cls_kernel(
    const float* __restrict__ hin, const float* __restrict__ W1,
    const float* __restrict__ b1, const float* __restrict__ W2,
    const float* __restrict__ b2, float* __restrict__ out, int N)
{
    __shared__ __align__(16) float w1[HD * 64];
    __shared__ __align__(16) float w2[64 * 40];
    __shared__ __align__(16) float hs[4][HD];
    __shared__ float ts[4][64];
    for (int i = threadIdx.x; i < HD * 64; i += 256) w1[i] = W1[i];
    for (int i = threadIdx.x; i < 64 * 40; i += 256) w2[i] = W2[i];
    int sub = threadIdx.x >> 6, t = threadIdx.x & 63;
    float b1j = b1[t];
    float b2j = (t < 40) ? b2[t] : 0.f;
    __syncthreads();
    for (int base = blockIdx.x * 4; base < N; base += gridDim.x * 4) {
        int i = base + sub; bool val = i < N;
        if (val) { hs[sub][t] = hin[(size_t)i * HD + t]; hs[sub][64 + t] = hin[(size_t)i * HD + 64 + t]; }
        __syncthreads();
        float acc = b1j;
        const float* hr = hs[sub];
        #pragma unroll 8
        for (int k = 0; k < HD; k += 4) {
            float4 hv = *(const float4*)(hr + k);
            acc = fmaf(hv.x, w1[(k + 0) * 64 + t], acc);
            acc = fmaf(hv.y, w1[(k + 1) * 64 + t], acc);
            acc = fmaf(hv.z, w1[(k + 2) * 64 + t], acc);
            acc = fmaf(hv.w, w1[(k + 3) * 64 + t], acc);
        }
        ts[sub][t] = fmaxf(acc, 0.f);
        __syncthreads();
        if (val && t < 40) {
            float o = b2j;
            const float* tr = ts[sub];
            #pragma unroll 8
            for (int k = 0; k < 64; k++) o = fmaf(tr[k], w2[k * 40 + t], o);
            out[(size_t)i * 40 + t] = o;
        }
        __syncthreads();
    }
}

extern "C" void kernel_launch(void* const* d_in, const int* in_sizes, int n_in,
                              void* d_out, int out_size, void* d_ws, size_t ws_size,
                              hipStream_t stream)
{
    const float* x      = (const float*)d_in[0];
    const int*   ei     = (const int*)d_in[1];
    const float* proj_W = (const float*)d_in[2];
    const float* proj_b = (const float*)d_in[3];
    const float* ln0_g  = (const float*)d_in[4];
    const float* ln0_b  = (const float*)d_in[5];
    const float* sim_W1 = (const float*)d_in[6];
    const float* sim_b1 = (const float*)d_in[7];
    const float* sim_W2 = (const float*)d_in[8];
    const float* sim_b2 = (const float*)d_in[9];
    const float* W_msg  = (const float*)d_in[10];
    const float* W_upd  = (const float*)d_in[11];
    const float* b_upd  = (const float*)d_in[12];
    const float* ln_g   = (const float*)d_in[13];
    const float* ln_b   = (const float*)d_in[14];
    const float* cls_W1 = (const float*)d_in[15];
    const float* cls_b1 = (const float*)d_in[16];
    const float* cls_W2 = (const float*)d_in[17];
    const float* cls_b2 = (const float*)d_in[18];

    int N = in_sizes[0] / 256;
    int E = in_sizes[1] / 2;
    int L = in_sizes[6] / (3 * HD * HD);
    int Etot = E + N;
    const int* srcA = ei;
    const int* dstA = ei + E;

    float* ws = (float*)d_ws;
    size_t nh = (size_t)N * HD;
    float* h       = ws;
    float* pre_agg = h + nh;
    float* score   = pre_agg + nh;
    float* wcomb   = score + Etot + 64;                      // L * 256*128 floats
    unsigned* hbf  = (unsigned*)(wcomb + (size_t)L * 32768); // N*64 uints
    unsigned short* w1bf = (unsigned short*)(hbf + nh / 2);
    int*   cnt    = (int*)(w1bf + (size_t)L * 49152);
    int*   rowptr = cnt + N;
    int*   cursor = rowptr + N + 1;
    int*   esrc   = cursor + N;
    int*   edst   = esrc + Etot;

    int gemm_blocks = (N + 31) / 32;

    // CSR build (edge_index constant across layers)
    hipMemsetAsync(cnt, 0, (size_t)N * sizeof(int), stream);
    hist_kernel<<<512, 256, 0, stream>>>(dstA, cnt, E, Etot);
    scan_kernel<<<1, 256, 0, stream>>>(cnt, rowptr, cursor, N, Etot);
    scatter_kernel<<<512, 256, 0, stream>>>(srcA, dstA, cursor, esrc, edst, E, Etot);

    // W1 -> bf16 fragment-major (all layers, once)
    int w1_total = L * 49152;
    w1bf_kernel<<<(w1_total + 255) / 256, 256, 0, stream>>>(sim_W1, w1bf, w1_total);

    // wcomb[l] = [ W_upd[l][0:128] ; W_msg[l] @ W_upd[l][128:256] ]
    int cp_total = L * 16384;
    copy_upd_kernel<<<(cp_total + 255) / 256, 256, 0, stream>>>(W_upd, wcomb, cp_total);
    for (int l = 0; l < L; l++) {
        gemm_rows_kernel<<<(128 + 31) / 32, 256, 0, stream>>>(
            W_msg + (size_t)l * 16384, 128, nullptr, 0,
            W_upd + (size_t)l * 32768 + 16384, nullptr, nullptr, nullptr, nullptr,
            wcomb + (size_t)l * 32768 + 16384, nullptr, 128);
    }

    // h = relu(LN(x @ proj_W + b)), hbf mirror
    gemm_rows_kernel<<<gemm_blocks, 256, 0, stream>>>(x, 256, x + 128, 256, proj_W, proj_b,
                                                      nullptr, ln0_g, ln0_b, h, hbf, N);

    int gather_blocks = (N + 3) / 4;          // 5000, divisible by 8
    for (int l = 0; l < L; l++) {
        edge_mfma_kernel<<<768, 256, 0, stream>>>(hbf, esrc, edst,
                                                  w1bf + (size_t)l * 49152, sim_b1 + l * HD,
                                                  sim_W2 + l * HD, sim_b2 + l, score, Etot);
        gather_kernel<<<gather_blocks, 256, 0, stream>>>(rowptr, esrc, score, hbf, pre_agg, N);
        gemm_rows_kernel<<<gemm_blocks, 256, 0, stream>>>(h, 128, pre_agg, 128,
                                                          wcomb + (size_t)l * 32768,
                                                          b_upd + l * HD, h,
                                                          ln_g + l * HD, ln_b + l * HD, h, hbf, N);
    }
    cls_kernel<<<768, 256, 0, stream>>>(h, cls_W1, cls_b1, cls_W2, cls_b2, (float*)d_out, N);
}